// Round 1
// baseline (9.518 us; speedup 1.0000x reference)
//
#include <hip/hip_runtime.h>

// TT embedding gather: out[t, e] = sum_r left[v_t/62500, r] * core2[r, (v_t%62500)*64 + e]
// where left[i*D1+j, c] = sum_b core0[0,i,b] * core1[b,j,c]  (8x8, tiny)
//
// Shapes: core0 (1,2,8), core1 (8,4,8), core2 (8,4000000,1), ids (16,512) int32.
// Output: (16,512,64) float32.

#define TT_D0   2
#define TT_D1   4
#define TT_D2   4000000
#define TT_RANK 8
#define TT_NTOK (16 * 512)
#define TT_EMB  64
#define TT_VDIV 62500   // TT_D2 / TT_EMB

__global__ __launch_bounds__(256) void TTEmbeddingLayer_84713934946739_kernel(
    const int*   __restrict__ ids,
    const float* __restrict__ core0,
    const float* __restrict__ core1,
    const float* __restrict__ core2,
    float*       __restrict__ out)
{
    __shared__ float left[TT_D0 * TT_D1][TT_RANK];

    const int tid = threadIdx.x;

    // Compute the 8x8 "left" matrix cooperatively (64 threads, 8 FMAs each).
    if (tid < TT_D0 * TT_D1 * TT_RANK) {
        const int c  = tid & (TT_RANK - 1);
        const int ij = tid >> 3;                 // i*D1 + j, 0..7
        const int i0 = ij / TT_D1;
        const int i1 = ij - i0 * TT_D1;
        float s = 0.f;
#pragma unroll
        for (int b = 0; b < TT_RANK; ++b)
            s += core0[i0 * TT_RANK + b] * core1[(b * TT_D1 + i1) * TT_RANK + c];
        left[ij][c] = s;
    }
    __syncthreads();

    // One wave (64 lanes) per token; lane = embed dim.
    const int wave = tid >> 6;                   // 0..3
    const int lane = tid & 63;                   // e
    const int tok  = blockIdx.x * 4 + wave;
    if (tok >= TT_NTOK) return;

    const int v    = ids[tok];
    const int i    = v / TT_VDIV;                // core-2 "row block" index, constant per token
    const int base = (v - i * TT_VDIV) * TT_EMB + lane;  // j index into D2, contiguous in lane

    float acc = 0.f;
#pragma unroll
    for (int r = 0; r < TT_RANK; ++r)
        acc += left[i][r] * core2[r * TT_D2 + base];

    out[tok * TT_EMB + lane] = acc;
}

extern "C" void kernel_launch(void* const* d_in, const int* in_sizes, int n_in,
                              void* d_out, int out_size, void* d_ws, size_t ws_size,
                              hipStream_t stream) {
    const int*   ids   = (const int*)  d_in[0];
    const float* core0 = (const float*)d_in[1];
    const float* core1 = (const float*)d_in[2];
    const float* core2 = (const float*)d_in[3];
    float*       out   = (float*)      d_out;

    const int blocks = TT_NTOK / 4;  // 4 tokens (waves) per 256-thread block
    TTEmbeddingLayer_84713934946739_kernel<<<blocks, 256, 0, stream>>>(
        ids, core0, core1, core2, out);
}